// Round 1
// baseline (280.566 us; speedup 1.0000x reference)
//
#include <hip/hip_runtime.h>
#include <math.h>

// Problem constants (MultiHeadCRA): B=8, C=1024, H=W=64
#define SDIM 4096      // spatial S = H*W
#define DDIM 128       // head_dim
#define RED 8          // reduced dim
#define HEADS 8
#define BATCH 8
#define BH 64          // BATCH*HEADS
#define CH 1024        // channels per batch = HEADS*DDIM

// workspace layout (floats):
//   avg    [8192]      @ 0       indexed by global channel row (b*1024 + h*128 + d)
//   wq_eff [BH*128]    @ 8192
//   vvec   [BH*128]    @ 16384
//   cconst [BH]        @ 24576
//   scores [BH*4096]   @ 32768   (attn written in-place)
#define WS_WQ  8192
#define WS_V   16384
#define WS_C   24576
#define WS_SC  32768

__inline__ __device__ float wave_reduce_sum(float v) {
#pragma unroll
    for (int o = 32; o > 0; o >>= 1) v += __shfl_down(v, o, 64);
    return v;
}
__inline__ __device__ float wave_reduce_max(float v) {
#pragma unroll
    for (int o = 32; o > 0; o >>= 1) v = fmaxf(v, __shfl_down(v, o, 64));
    return v;
}

// K1: per-channel spatial mean. One block (256 thr) per channel row (8192 rows).
__global__ __launch_bounds__(256) void k_avg(const float* __restrict__ x,
                                             float* __restrict__ ws) {
    const int row = blockIdx.x;                 // 0..8191
    const int t = threadIdx.x;                  // 0..255
    const float4* xr = (const float4*)(x + (size_t)row * SDIM);
    float s = 0.f;
#pragma unroll
    for (int p = 0; p < 4; ++p) {
        float4 v = xr[t + 256 * p];
        s += v.x + v.y + v.z + v.w;
    }
    s = wave_reduce_sum(s);
    __shared__ float part[4];
    const int wave = t >> 6, lane = t & 63;
    if (lane == 0) part[wave] = s;
    __syncthreads();
    if (t == 0) {
        float tot = part[0] + part[1] + part[2] + part[3];
        ws[row] = tot * (1.0f / SDIM);
    }
}

// K2: per-(b,h) head math: k (red), wq_eff (d), v (d), score const. 64 blocks x 128 thr.
__global__ __launch_bounds__(128) void k_headmath(
        const float* __restrict__ Wq, const float* __restrict__ bq,
        const float* __restrict__ Wk, const float* __restrict__ bk,
        const float* __restrict__ Wv, const float* __restrict__ bv,
        float* __restrict__ ws) {
    const int bh = blockIdx.x;
    const int b = bh >> 3, h = bh & 7;
    const int t = threadIdx.x;                  // 0..127
    __shared__ float avgs[DDIM];
    __shared__ float kk[RED];
    avgs[t] = ws[b * CH + h * DDIM + t];
    __syncthreads();
    if (t < RED) {
        const float* wkr = Wk + (h * RED + t) * DDIM;
        float acc = 0.f;
#pragma unroll 8
        for (int d = 0; d < DDIM; ++d) acc += wkr[d] * avgs[d];
        kk[t] = acc + bk[h * RED + t];
    }
    __syncthreads();
    {   // wq_eff[d] = sum_r Wq[h,r,d] * k[r]
        float acc = 0.f;
#pragma unroll
        for (int r = 0; r < RED; ++r) acc += Wq[(h * RED + r) * DDIM + t] * kk[r];
        ws[WS_WQ + bh * DDIM + t] = acc;
    }
    {   // v[e] = sum_d Wv[h,e,d] * avg[d] + bv[h,e]
        const float* wvr = Wv + (h * DDIM + t) * DDIM;
        float acc = 0.f;
#pragma unroll 8
        for (int d = 0; d < DDIM; ++d) acc += wvr[d] * avgs[d];
        ws[WS_V + bh * DDIM + t] = acc + bv[h * DDIM + t];
    }
    if (t == 0) {   // score constant = sum_r bq[h,r] * k[r]
        float acc = 0.f;
#pragma unroll
        for (int r = 0; r < RED; ++r) acc += bq[h * RED + r] * kk[r];
        ws[WS_C + bh] = acc;
    }
}

// K3: scores[bh, s] = sum_d xh[bh,d,s] * wq_eff[bh,d] + const.
// 256 blocks: (bh, s-chunk of 1024); 256 thr, each owns a float4 of s.
__global__ __launch_bounds__(256) void k_scores(const float* __restrict__ x,
                                                float* __restrict__ ws) {
    const int blk = blockIdx.x;
    const int bh = blk >> 2, chunk = blk & 3;
    const int b = bh >> 3, h = bh & 7;
    const int t = threadIdx.x;
    __shared__ float wqs[DDIM];
    __shared__ float cc;
    if (t < DDIM) wqs[t] = ws[WS_WQ + bh * DDIM + t];
    if (t == 0) cc = ws[WS_C + bh];
    __syncthreads();
    const int s0 = chunk * 1024 + t * 4;
    const float* xb = x + (size_t)(b * CH + h * DDIM) * SDIM + s0;
    float4 acc;
    acc.x = cc; acc.y = cc; acc.z = cc; acc.w = cc;
#pragma unroll 8
    for (int d = 0; d < DDIM; ++d) {
        float4 xv = *(const float4*)(xb + (size_t)d * SDIM);
        const float w = wqs[d];
        acc.x += xv.x * w; acc.y += xv.y * w; acc.z += xv.z * w; acc.w += xv.w * w;
    }
    *(float4*)(ws + WS_SC + (size_t)bh * SDIM + s0) = acc;
}

// K4: softmax over S per (b,h), in place. 64 blocks x 256 thr, 16 scores/thread.
__global__ __launch_bounds__(256) void k_softmax(float* __restrict__ ws) {
    const int bh = blockIdx.x;
    const int t = threadIdx.x;
    float4* sc = (float4*)(ws + WS_SC + (size_t)bh * SDIM);
    float4 vals[4];
    float m = -1e30f;
#pragma unroll
    for (int p = 0; p < 4; ++p) {
        vals[p] = sc[t + 256 * p];
        m = fmaxf(m, fmaxf(fmaxf(vals[p].x, vals[p].y), fmaxf(vals[p].z, vals[p].w)));
    }
    m = wave_reduce_max(m);
    __shared__ float smax[4];
    __shared__ float ssum[4];
    const int wave = t >> 6, lane = t & 63;
    if (lane == 0) smax[wave] = m;
    __syncthreads();
    const float gm = fmaxf(fmaxf(smax[0], smax[1]), fmaxf(smax[2], smax[3]));
    float sum = 0.f;
#pragma unroll
    for (int p = 0; p < 4; ++p) {
        vals[p].x = expf(vals[p].x - gm);
        vals[p].y = expf(vals[p].y - gm);
        vals[p].z = expf(vals[p].z - gm);
        vals[p].w = expf(vals[p].w - gm);
        sum += vals[p].x + vals[p].y + vals[p].z + vals[p].w;
    }
    sum = wave_reduce_sum(sum);
    if (lane == 0) ssum[wave] = sum;
    __syncthreads();
    const float inv = 1.0f / (ssum[0] + ssum[1] + ssum[2] + ssum[3]);
#pragma unroll
    for (int p = 0; p < 4; ++p) {
        float4 o;
        o.x = vals[p].x * inv; o.y = vals[p].y * inv;
        o.z = vals[p].z * inv; o.w = vals[p].w * inv;
        sc[t + 256 * p] = o;
    }
}

// K5: out[b, h*128+e, s] = attn[bh, s] * v[bh, e]. Pure write-bound broadcast.
// Grid-stride over 2^23 float4s.
__global__ __launch_bounds__(256) void k_out(const float* __restrict__ ws,
                                             float* __restrict__ out) {
    const float4* attn = (const float4*)(ws + WS_SC);
    const float* vv = ws + WS_V;
    const size_t total = (size_t)BATCH * CH * (SDIM / 4);   // 8388608
    const size_t stride = (size_t)gridDim.x * blockDim.x;
    for (size_t f = (size_t)blockIdx.x * blockDim.x + threadIdx.x; f < total; f += stride) {
        const int s4 = (int)(f & 1023);
        const int ce = (int)((f >> 10) & 1023);
        const int b = (int)(f >> 20);
        const int bh = (b << 3) | (ce >> 7);
        const int e = ce & 127;
        const float4 a = attn[bh * 1024 + s4];
        const float vx = vv[bh * 128 + e];
        float4 o;
        o.x = a.x * vx; o.y = a.y * vx; o.z = a.z * vx; o.w = a.w * vx;
        ((float4*)out)[f] = o;
    }
}

extern "C" void kernel_launch(void* const* d_in, const int* in_sizes, int n_in,
                              void* d_out, int out_size, void* d_ws, size_t ws_size,
                              hipStream_t stream) {
    const float* x  = (const float*)d_in[0];
    const float* Wq = (const float*)d_in[1];
    const float* bq = (const float*)d_in[2];
    const float* Wk = (const float*)d_in[3];
    const float* bk = (const float*)d_in[4];
    const float* Wv = (const float*)d_in[5];
    const float* bv = (const float*)d_in[6];
    float* out = (float*)d_out;
    float* ws  = (float*)d_ws;

    k_avg<<<8192, 256, 0, stream>>>(x, ws);
    k_headmath<<<BH, 128, 0, stream>>>(Wq, bq, Wk, bk, Wv, bv, ws);
    k_scores<<<256, 256, 0, stream>>>(x, ws);
    k_softmax<<<BH, 256, 0, stream>>>(ws);
    k_out<<<8192, 256, 0, stream>>>(ws, out);
}

// Round 3
// 269.309 us; speedup vs baseline: 1.0418x; 1.0418x over previous
//
#include <hip/hip_runtime.h>
#include <math.h>

// Problem constants (MultiHeadCRA): B=8, C=1024, H=W=64
#define SDIM 4096      // spatial S = H*W
#define DDIM 128       // head_dim
#define RED 8          // reduced dim
#define BATCH 8
#define BH 64          // BATCH*HEADS
#define CH 1024        // channels per batch = HEADS*DDIM

// native 16B vector for nontemporal builtins (HIP's float4 is a class type,
// rejected by __builtin_nontemporal_store)
typedef float vfloat4 __attribute__((ext_vector_type(4)));

// workspace layout (floats):
//   avg    [8192]       @ 0       indexed by (b*1024 + h*128 + d)
//   vvec   [BH*128]     @ 8192
//   scores [BH*4096]    @ 16384   (attn written in-place)
#define WS_V   8192
#define WS_SC  16384

__inline__ __device__ float wave_reduce_sum(float v) {
#pragma unroll
    for (int o = 32; o > 0; o >>= 1) v += __shfl_down(v, o, 64);
    return v;
}
__inline__ __device__ float wave_reduce_max(float v) {
#pragma unroll
    for (int o = 32; o > 0; o >>= 1) v = fmaxf(v, __shfl_down(v, o, 64));
    return v;
}

// K1: per-channel spatial mean. One block (256 thr) per channel row (8192 rows).
__global__ __launch_bounds__(256) void k_avg(const float* __restrict__ x,
                                             float* __restrict__ ws) {
    const int row = blockIdx.x;                 // 0..8191
    const int t = threadIdx.x;                  // 0..255
    const float4* xr = (const float4*)(x + (size_t)row * SDIM);
    float s = 0.f;
#pragma unroll
    for (int p = 0; p < 4; ++p) {
        float4 v = xr[t + 256 * p];
        s += v.x + v.y + v.z + v.w;
    }
    s = wave_reduce_sum(s);
    __shared__ float part[4];
    const int wave = t >> 6, lane = t & 63;
    if (lane == 0) part[wave] = s;
    __syncthreads();
    if (t == 0) {
        float tot = part[0] + part[1] + part[2] + part[3];
        ws[row] = tot * (1.0f / SDIM);
    }
}

// K2: scores[bh, s] = sum_d x[bh*128+d, s] * wq_eff[bh,d] + const, with the
// per-(b,h) head math (k, wq_eff, const) computed inline per block.
// Grid: 512 blocks = 64 bh x 8 s-chunks of 512; 256 thr, float2 per thread.
__global__ __launch_bounds__(256) void k_scores(
        const float* __restrict__ x,
        const float* __restrict__ Wq, const float* __restrict__ bq,
        const float* __restrict__ Wk, const float* __restrict__ bk,
        float* __restrict__ ws) {
    const int blk = blockIdx.x;
    const int bh = blk >> 3, chunk = blk & 7;
    const int b = bh >> 3, h = bh & 7;
    const int t = threadIdx.x;

    __shared__ float avgs[DDIM];
    __shared__ float kk[RED];
    __shared__ float wqs[DDIM];
    __shared__ float cc;

    if (t < DDIM) avgs[t] = ws[b * CH + h * DDIM + t];
    __syncthreads();
    if (t < RED) {
        const float* wkr = Wk + (h * RED + t) * DDIM;
        float acc = 0.f;
#pragma unroll 8
        for (int d = 0; d < DDIM; ++d) acc += wkr[d] * avgs[d];
        kk[t] = acc + bk[h * RED + t];
    }
    __syncthreads();
    if (t < DDIM) {
        float acc = 0.f;
#pragma unroll
        for (int r = 0; r < RED; ++r) acc += Wq[(h * RED + r) * DDIM + t] * kk[r];
        wqs[t] = acc;
    }
    if (t == 0) {
        float acc = 0.f;
#pragma unroll
        for (int r = 0; r < RED; ++r) acc += bq[h * RED + r] * kk[r];
        cc = acc;
    }
    __syncthreads();

    const int s0 = chunk * 512 + t * 2;
    const float* xb = x + (size_t)(b * CH + h * DDIM) * SDIM + s0;
    float2 acc;
    const float c = cc;
    acc.x = c; acc.y = c;
#pragma unroll 16
    for (int d = 0; d < DDIM; ++d) {
        float2 xv = *(const float2*)(xb + (size_t)d * SDIM);
        const float w = wqs[d];
        acc.x += xv.x * w; acc.y += xv.y * w;
    }
    *(float2*)(ws + WS_SC + (size_t)bh * SDIM + s0) = acc;
}

// K3: per-(b,h): softmax over S in place + v = Wv@avg + bv. 64 blocks x 256 thr.
__global__ __launch_bounds__(256) void k_softmax_v(
        const float* __restrict__ Wv, const float* __restrict__ bv,
        float* __restrict__ ws) {
    const int bh = blockIdx.x;
    const int b = bh >> 3, h = bh & 7;
    const int t = threadIdx.x;

    __shared__ float avgs[DDIM];
    if (t < DDIM) avgs[t] = ws[b * CH + h * DDIM + t];
    __syncthreads();
    if (t < DDIM) {
        const float* wvr = Wv + (h * DDIM + t) * DDIM;
        float acc = 0.f;
#pragma unroll 8
        for (int d = 0; d < DDIM; ++d) acc += wvr[d] * avgs[d];
        ws[WS_V + bh * DDIM + t] = acc + bv[h * DDIM + t];
    }

    float4* sc = (float4*)(ws + WS_SC + (size_t)bh * SDIM);
    float4 vals[4];
    float m = -1e30f;
#pragma unroll
    for (int p = 0; p < 4; ++p) {
        vals[p] = sc[t + 256 * p];
        m = fmaxf(m, fmaxf(fmaxf(vals[p].x, vals[p].y), fmaxf(vals[p].z, vals[p].w)));
    }
    m = wave_reduce_max(m);
    __shared__ float smax[4];
    __shared__ float ssum[4];
    const int wave = t >> 6, lane = t & 63;
    if (lane == 0) smax[wave] = m;
    __syncthreads();
    const float gm = fmaxf(fmaxf(smax[0], smax[1]), fmaxf(smax[2], smax[3]));
    float sum = 0.f;
#pragma unroll
    for (int p = 0; p < 4; ++p) {
        vals[p].x = expf(vals[p].x - gm);
        vals[p].y = expf(vals[p].y - gm);
        vals[p].z = expf(vals[p].z - gm);
        vals[p].w = expf(vals[p].w - gm);
        sum += vals[p].x + vals[p].y + vals[p].z + vals[p].w;
    }
    sum = wave_reduce_sum(sum);
    if (lane == 0) ssum[wave] = sum;
    __syncthreads();
    const float inv = 1.0f / (ssum[0] + ssum[1] + ssum[2] + ssum[3]);
#pragma unroll
    for (int p = 0; p < 4; ++p) {
        float4 o;
        o.x = vals[p].x * inv; o.y = vals[p].y * inv;
        o.z = vals[p].z * inv; o.w = vals[p].w * inv;
        sc[t + 256 * p] = o;
    }
}

// K4: out[b, h*128+e, s] = attn[bh, s] * v[bh, e]. Write-bound broadcast.
__global__ __launch_bounds__(256) void k_out(const float* __restrict__ ws,
                                             float* __restrict__ out) {
    const vfloat4* attn = (const vfloat4*)(ws + WS_SC);
    const float* vv = ws + WS_V;
    const size_t total = (size_t)BATCH * CH * (SDIM / 4);   // 8388608
    const size_t stride = (size_t)gridDim.x * blockDim.x;
    for (size_t f = (size_t)blockIdx.x * blockDim.x + threadIdx.x; f < total; f += stride) {
        const int s4 = (int)(f & 1023);
        const int ce = (int)((f >> 10) & 1023);
        const int b = (int)(f >> 20);
        const int bh = (b << 3) | (ce >> 7);
        const int e = ce & 127;
        const vfloat4 a = attn[bh * 1024 + s4];
        const float vx = vv[bh * 128 + e];
        vfloat4 o = a * vx;
        __builtin_nontemporal_store(o, ((vfloat4*)out) + f);
    }
}

extern "C" void kernel_launch(void* const* d_in, const int* in_sizes, int n_in,
                              void* d_out, int out_size, void* d_ws, size_t ws_size,
                              hipStream_t stream) {
    const float* x  = (const float*)d_in[0];
    const float* Wq = (const float*)d_in[1];
    const float* bq = (const float*)d_in[2];
    const float* bk = (const float*)d_in[4];
    const float* Wk = (const float*)d_in[3];
    const float* Wv = (const float*)d_in[5];
    const float* bv = (const float*)d_in[6];
    float* out = (float*)d_out;
    float* ws  = (float*)d_ws;

    k_avg<<<8192, 256, 0, stream>>>(x, ws);
    k_scores<<<512, 256, 0, stream>>>(x, Wq, bq, Wk, bk, ws);
    k_softmax_v<<<BH, 256, 0, stream>>>(Wv, bv, ws);
    k_out<<<8192, 256, 0, stream>>>(ws, out);
}